// Round 15
// baseline (88.303 us; speedup 1.0000x reference)
//
#include <hip/hip_runtime.h>
#include <math.h>

#define HW1 (1024 * 1024)
#define WID 1024
#define HEI 1024
#define NMAIN 1024           // (gy 0..255) x (quarter q 0..3)
#define NSOB  384            // sobel: 3 planes x 256 y-tiles x 128 x-tiles / 256 thr
#define NBLK  (NMAIN + NSOB)

typedef float f32x4 __attribute__((ext_vector_type(4)));
typedef _Float16 f16;

// Block-level reduce (wave shfl + LDS) then one atomicAdd per block.
__device__ __forceinline__ void block_atomic_add(float v, float* target, volatile float* sdata) {
#pragma unroll
    for (int off = 32; off > 0; off >>= 1)
        v += __shfl_down(v, off, 64);
    const int lane = threadIdx.x & 63;
    const int wv   = threadIdx.x >> 6;
    if (lane == 0) sdata[wv] = v;
    __syncthreads();
    if (threadIdx.x == 0) {
        float s = 0.f;
        for (int i = 0; i < 4; ++i) s += sdata[i];
        atomicAdd(target, s);
    }
    __syncthreads();
}

// Blocks [0,1024): main. Block=(gy,q): 4 image rows x 256 cols, all channels+batches.
//   1 float4 per lane per (b,c) per array; pd in f16 -> LDS 12.7 KB -> high occupancy.
// Blocks [1024,1408): Sobel on batch-0 (4x8 tile/thread) — rides free (R13 lesson).
__global__ __launch_bounds__(256) void k_A(const float* __restrict__ A,
                                           const float* __restrict__ B,
                                           float* __restrict__ acc) {
    __shared__ f16 pdl[8][3][4][66];   // [b][c][yl][slot]; slot 1..64 data, 0/65 ghosts
    __shared__ float s1[4];

    const int tid = threadIdx.x;

    if (blockIdx.x < NMAIN) {
        const int gy = blockIdx.x >> 2;      // pool row 0..255
        const int q  = blockIdx.x & 3;       // quarter 0..3
        const int xl = tid & 63;
        const int yl = tid >> 6;             // image row within pool row
        const int y  = gy * 4 + yl;
        const int rbase = y * 256 + q * 64;  // float4 index of this quarter-row

        const f32x4* A4 = reinterpret_cast<const f32x4*>(A);
        const f32x4* B4 = reinterpret_cast<const f32x4*>(B);

        float na2[3][4], nb2[3][4], dt[3][4];   // [c][j] — static indexing
#pragma unroll
        for (int c = 0; c < 3; ++c)
#pragma unroll
            for (int j = 0; j < 4; ++j) { na2[c][j] = 0.f; nb2[c][j] = 0.f; dt[c][j] = 0.f; }
        float r_sum = 0.f;

#pragma unroll 2
        for (int b = 0; b < 8; ++b) {
#pragma unroll
            for (int c = 0; c < 3; ++c) {
                const int pbase = (b * 3 + c) * (HW1 / 4) + rbase;
                const f32x4 a0 = A4[pbase + xl];
                const f32x4 b0 = B4[pbase + xl];
                float pd0 = 0.f;
#pragma unroll
                for (int j = 0; j < 4; ++j) {
                    const float a = a0[j], t = b0[j];
                    na2[c][j] += a * a; nb2[c][j] += t * t; dt[c][j] += a * t;
                    r_sum += fabsf(a - t); pd0 += t - a;
                }
                pdl[b][c][yl][1 + xl] = (f16)pd0;
            }
        }

        // ---- ghost columns: G-channel neighbor pool cells, both sides ----
        // 8 b x 4 yl x 2 sides = 64 slots; zero-pad at image edges.
        if (tid < 64) {
            const int b2   = tid >> 3;
            const int yl2  = (tid >> 1) & 3;
            const int side = tid & 1;                 // 0 = left, 1 = right
            const int f4   = q * 64 + (side ? 64 : -1);
            float pg = 0.f;
            if (f4 >= 0 && f4 < 256) {
                const int gp = (b2 * 3 + 1) * (HW1 / 4) + (gy * 4 + yl2) * 256 + f4;
                const f32x4 ga = A4[gp];
                const f32x4 gb = B4[gp];
                pg = (gb[0] - ga[0]) + (gb[1] - ga[1]) + (gb[2] - ga[2]) + (gb[3] - ga[3]);
            }
            pdl[b2][1][yl2][side ? 65 : 0] = (f16)pg;
        }

        // ---- c_loss: thread-local over its 4 pixels ----
        float c_sum = 0.f;
#pragma unroll
        for (int j = 0; j < 4; ++j) {
            float cs = 0.f;
#pragma unroll
            for (int c = 0; c < 3; ++c) {
                const float na = fmaxf(sqrtf(na2[c][j]), 1e-12f);
                const float nb = fmaxf(sqrtf(nb2[c][j]), 1e-12f);
                cs += dt[c][j] / (na * nb);
            }
            cs = fminf(fmaxf(cs, -1.0f + 1e-7f), 1.0f - 1e-7f);
            c_sum += acosf(cs);
        }

        __syncthreads();

        // ---- p_loss in-block: 8 b x 64 cells = 512 items, 2/thread ----
        // pdl holds 16x pool values; fold /16^2 into one 1/256 scale.
        float p_sum = 0.f;
#pragma unroll
        for (int i = 0; i < 2; ++i) {
            const int item = i * 256 + tid;
            const int b2 = item >> 6;
            const int x  = item & 63;
            float g = 0.f, gl = 0.f, gr = 0.f, rr = 0.f, bb = 0.f;
#pragma unroll
            for (int yy = 0; yy < 4; ++yy) {
                g  += (float)pdl[b2][1][yy][1 + x];
                gl += (float)pdl[b2][1][yy][x];
                gr += (float)pdl[b2][1][yy][2 + x];
                rr += (float)pdl[b2][0][yy][1 + x];
                bb += (float)pdl[b2][2][yy][1 + x];
            }
            const float d0 = g - gl;
            const float d1 = g - gr;
            const float d2 = g - rr;
            const float d3 = g - bb;
            p_sum += d0 * d0 + d1 * d1 + d2 * d2 + d3 * d3;
        }
        p_sum *= (1.0f / 256.0f);

        block_atomic_add(r_sum, acc + 0, s1);
        block_atomic_add(c_sum, acc + 1, s1);
        block_atomic_add(p_sum, acc + 3, s1);
    } else {
        // ---------------- Sobel path: 4x8 output tile per thread ----------------
        const int t   = (blockIdx.x - NMAIN) * 256 + tid;  // 0 .. 98303
        const int xt  = t & 127;
        const int rem = t >> 7;
        const int yt  = rem & 255;
        const int c   = rem >> 8;          // 0..2
        const int x0  = xt * 8;
        const int y0  = yt * 4;

        const float* Ap = A + (size_t)c * HW1;
        const float* Bp = B + (size_t)c * HW1;

        float rd[6][8];  // rowdiff(y,x) = d(y,x-1) - d(y,x+1), rows y0-1..y0+4
#pragma unroll
        for (int r = 0; r < 6; ++r) {
            const int yy = y0 - 1 + r;
            if (yy < 0 || yy >= HEI) {
#pragma unroll
                for (int j = 0; j < 8; ++j) rd[r][j] = 0.f;
                continue;
            }
            const float* ap = Ap + (size_t)yy * WID;
            const float* bp = Bp + (size_t)yy * WID;
            const float4 a4 = *reinterpret_cast<const float4*>(ap + x0);
            const float4 a5 = *reinterpret_cast<const float4*>(ap + x0 + 4);
            const float4 b4 = *reinterpret_cast<const float4*>(bp + x0);
            const float4 b5 = *reinterpret_cast<const float4*>(bp + x0 + 4);
            const float dm = (x0 > 0)    ? (ap[x0 - 1] - bp[x0 - 1]) : 0.f;
            const float dp = (x0 < 1016) ? (ap[x0 + 8] - bp[x0 + 8]) : 0.f;
            const float d0 = a4.x - b4.x, d1 = a4.y - b4.y, d2 = a4.z - b4.z, d3 = a4.w - b4.w;
            const float d4 = a5.x - b5.x, d5 = a5.y - b5.y, d6 = a5.z - b5.z, d7 = a5.w - b5.w;
            rd[r][0] = dm - d1;
            rd[r][1] = d0 - d2;
            rd[r][2] = d1 - d3;
            rd[r][3] = d2 - d4;
            rd[r][4] = d3 - d5;
            rd[r][5] = d4 - d6;
            rd[r][6] = d5 - d7;
            rd[r][7] = d6 - dp;
        }

        float s_sum = 0.f;
#pragma unroll
        for (int o = 0; o < 4; ++o)
#pragma unroll
            for (int j = 0; j < 8; ++j)
                s_sum += fabsf(rd[o][j] + 2.f * rd[o + 1][j] + rd[o + 2][j]);

        block_atomic_add(s_sum, acc + 2, s1);
    }
}

// Combine: out = W_C*c + W_R*r + W_P*p + W_S*s
__global__ void k_final(const float* __restrict__ acc, float* __restrict__ out) {
    const float r = acc[0] * (1.0f / 25165824.0f);  // mean over 8*3*1024*1024
    const float c = acc[1];
    const float s = acc[2];
    const float p = acc[3] * (1.0f / 524288.0f);    // mean over 8*256*256
    out[0] = 0.5f * c + 1.0f * r + 1.0f * p + 0.1f * s;
}

extern "C" void kernel_launch(void* const* d_in, const int* in_sizes, int n_in,
                              void* d_out, int out_size, void* d_ws, size_t ws_size,
                              hipStream_t stream) {
    const float* A = (const float*)d_in[0];  // predictions
    const float* B = (const float*)d_in[1];  // targets
    float* acc = (float*)d_ws;               // acc[0..3]

    hipMemsetAsync(acc, 0, 64 * sizeof(float), stream);
    hipLaunchKernelGGL(k_A,     dim3(NBLK), dim3(256), 0, stream, A, B, acc);
    hipLaunchKernelGGL(k_final, dim3(1),    dim3(1),   0, stream, acc, (float*)d_out);
}

// Round 16
// 63.106 us; speedup vs baseline: 1.3993x; 1.3993x over previous
//
#include <hip/hip_runtime.h>
#include <math.h>

#define HW1 (1024 * 1024)
#define WID 1024
#define HEI 1024
#define NMAIN 512            // (gy 0..255) x (h 0..1)
#define NSOB  384            // sobel: 3 planes x 256 y-tiles x 128 x-tiles / 256 thr
#define NBLK  (NMAIN + NSOB)

typedef float f32x4 __attribute__((ext_vector_type(4)));
typedef _Float16 f16;

// Block-level reduce (wave shfl + LDS) then one atomicAdd per block.
__device__ __forceinline__ void block_atomic_add(float v, float* target, volatile float* sdata) {
#pragma unroll
    for (int off = 32; off > 0; off >>= 1)
        v += __shfl_down(v, off, 64);
    const int lane = threadIdx.x & 63;
    const int wv   = threadIdx.x >> 6;
    if (lane == 0) sdata[wv] = v;
    __syncthreads();
    if (threadIdx.x == 0) {
        float s = 0.f;
        for (int i = 0; i < 4; ++i) s += sdata[i];
        atomicAdd(target, s);
    }
    __syncthreads();
}

// R13 structure (measured 63.4 us) with pd in f16 (LDS 50 -> 25 KB).
// Blocks [0,512): main. Block=(gy,h): 4 image rows x 512 cols, ALL 3 channels.
//  - r_loss, c_loss thread-local (channels in-thread)
//  - pd (pooled diff, f16) -> LDS [8][3][4][130] w/ ghost cols; p_loss in-block.
// Blocks [512,896): Sobel on batch-0, 4x8 output tile per thread (rides free).
__global__ __launch_bounds__(256) void k_A(const float* __restrict__ A,
                                           const float* __restrict__ B,
                                           float* __restrict__ acc) {
    __shared__ f16 pd[8][3][4][130];   // [b][c][yl][slot]; slot 1..128 data, 0/129 ghost
    __shared__ float s1[4];

    const int tid = threadIdx.x;

    if (blockIdx.x < NMAIN) {
        const int gy = blockIdx.x >> 1;      // pool row 0..255
        const int h  = blockIdx.x & 1;       // half-row
        const int xl = tid & 63;
        const int yl = tid >> 6;             // image row within pool row
        const int y  = gy * 4 + yl;
        const int rbase = y * 256 + h * 128; // float4 index of this half-row

        const f32x4* A4 = reinterpret_cast<const f32x4*>(A);
        const f32x4* B4 = reinterpret_cast<const f32x4*>(B);

        float na2[3][8], nb2[3][8], dt[3][8];   // [c][pixel] — all static indexing
#pragma unroll
        for (int c = 0; c < 3; ++c)
#pragma unroll
            for (int j = 0; j < 8; ++j) { na2[c][j] = 0.f; nb2[c][j] = 0.f; dt[c][j] = 0.f; }
        float r_sum = 0.f;

#pragma unroll 2
        for (int b = 0; b < 8; ++b) {
#pragma unroll
            for (int c = 0; c < 3; ++c) {
                const int pbase = (b * 3 + c) * (HW1 / 4) + rbase;
                const f32x4 a0 = A4[pbase + xl];
                const f32x4 a1 = A4[pbase + 64 + xl];
                const f32x4 b0 = B4[pbase + xl];
                const f32x4 b1 = B4[pbase + 64 + xl];
                float pd0 = 0.f, pd1 = 0.f;
#pragma unroll
                for (int j = 0; j < 4; ++j) {
                    const float a = a0[j], t = b0[j];
                    na2[c][j] += a * a; nb2[c][j] += t * t; dt[c][j] += a * t;
                    r_sum += fabsf(a - t); pd0 += t - a;
                }
#pragma unroll
                for (int j = 0; j < 4; ++j) {
                    const float a = a1[j], t = b1[j];
                    na2[c][4 + j] += a * a; nb2[c][4 + j] += t * t; dt[c][4 + j] += a * t;
                    r_sum += fabsf(a - t); pd1 += t - a;
                }
                pd[b][c][yl][1 + xl]  = (f16)pd0;
                pd[b][c][yl][65 + xl] = (f16)pd1;
            }
        }

        // ---- ghost columns (outside hot loop) ----
        if (tid < 192) {
            const int side = tid & 1;            // 0 = slot 0, 1 = slot 129
            const int yl2  = (tid >> 1) & 3;
            const int c2   = (tid >> 3) % 3;
            const int b2   = tid / 24;
            const int dataside = (h == 0) ? 1 : 0;
            if (!(c2 == 1 && side == dataside))
                pd[b2][c2][yl2][side ? 129 : 0] = (f16)0.f;
        } else if (tid < 224) {
            const int i2  = tid - 192;
            const int b2  = i2 >> 2;
            const int yl2 = i2 & 3;
            const int gcol = (h == 0) ? 128 : 127;   // neighbor pool cell's float4 col
            const int slot = (h == 0) ? 129 : 0;
            const int gp = (b2 * 3 + 1) * (HW1 / 4) + (gy * 4 + yl2) * 256 + gcol;
            const f32x4 ga = A4[gp];
            const f32x4 gb = B4[gp];
            pd[b2][1][yl2][slot] = (f16)((gb[0] - ga[0]) + (gb[1] - ga[1])
                                       + (gb[2] - ga[2]) + (gb[3] - ga[3]));
        }

        // ---- c_loss: thread-local over its 8 pixels ----
        float c_sum = 0.f;
#pragma unroll
        for (int j = 0; j < 8; ++j) {
            float cs = 0.f;
#pragma unroll
            for (int c = 0; c < 3; ++c) {
                const float na = fmaxf(sqrtf(na2[c][j]), 1e-12f);
                const float nb = fmaxf(sqrtf(nb2[c][j]), 1e-12f);
                cs += dt[c][j] / (na * nb);
            }
            cs = fminf(fmaxf(cs, -1.0f + 1e-7f), 1.0f - 1e-7f);
            c_sum += acosf(cs);
        }

        __syncthreads();

        // ---- p_loss in-block: 8 b x 128 cells = 1024 items, 4/thread ----
        // pd holds 16x pool values; fold /16^2 into one 1/256 scale.
        float p_sum = 0.f;
#pragma unroll
        for (int i = 0; i < 4; ++i) {
            const int item = i * 256 + tid;
            const int b2 = item >> 7;
            const int x  = item & 127;
            float g = 0.f, gl = 0.f, gr = 0.f, rr = 0.f, bb = 0.f;
#pragma unroll
            for (int yy = 0; yy < 4; ++yy) {
                g  += (float)pd[b2][1][yy][1 + x];
                gl += (float)pd[b2][1][yy][x];
                gr += (float)pd[b2][1][yy][2 + x];
                rr += (float)pd[b2][0][yy][1 + x];
                bb += (float)pd[b2][2][yy][1 + x];
            }
            const float d0 = g - gl;
            const float d1 = g - gr;
            const float d2 = g - rr;
            const float d3 = g - bb;
            p_sum += d0 * d0 + d1 * d1 + d2 * d2 + d3 * d3;
        }
        p_sum *= (1.0f / 256.0f);

        block_atomic_add(r_sum, acc + 0, s1);
        block_atomic_add(c_sum, acc + 1, s1);
        block_atomic_add(p_sum, acc + 3, s1);
    } else {
        // ---------------- Sobel path: 4x8 output tile per thread ----------------
        const int t   = (blockIdx.x - NMAIN) * 256 + tid;  // 0 .. 98303
        const int xt  = t & 127;
        const int rem = t >> 7;
        const int yt  = rem & 255;
        const int c   = rem >> 8;          // 0..2
        const int x0  = xt * 8;
        const int y0  = yt * 4;

        const float* Ap = A + (size_t)c * HW1;
        const float* Bp = B + (size_t)c * HW1;

        float rd[6][8];  // rowdiff(y,x) = d(y,x-1) - d(y,x+1), rows y0-1..y0+4
#pragma unroll
        for (int r = 0; r < 6; ++r) {
            const int yy = y0 - 1 + r;
            if (yy < 0 || yy >= HEI) {
#pragma unroll
                for (int j = 0; j < 8; ++j) rd[r][j] = 0.f;
                continue;
            }
            const float* ap = Ap + (size_t)yy * WID;
            const float* bp = Bp + (size_t)yy * WID;
            const float4 a4 = *reinterpret_cast<const float4*>(ap + x0);
            const float4 a5 = *reinterpret_cast<const float4*>(ap + x0 + 4);
            const float4 b4 = *reinterpret_cast<const float4*>(bp + x0);
            const float4 b5 = *reinterpret_cast<const float4*>(bp + x0 + 4);
            const float dm = (x0 > 0)    ? (ap[x0 - 1] - bp[x0 - 1]) : 0.f;
            const float dp = (x0 < 1016) ? (ap[x0 + 8] - bp[x0 + 8]) : 0.f;
            const float d0 = a4.x - b4.x, d1 = a4.y - b4.y, d2 = a4.z - b4.z, d3 = a4.w - b4.w;
            const float d4 = a5.x - b5.x, d5 = a5.y - b5.y, d6 = a5.z - b5.z, d7 = a5.w - b5.w;
            rd[r][0] = dm - d1;
            rd[r][1] = d0 - d2;
            rd[r][2] = d1 - d3;
            rd[r][3] = d2 - d4;
            rd[r][4] = d3 - d5;
            rd[r][5] = d4 - d6;
            rd[r][6] = d5 - d7;
            rd[r][7] = d6 - dp;
        }

        float s_sum = 0.f;
#pragma unroll
        for (int o = 0; o < 4; ++o)
#pragma unroll
            for (int j = 0; j < 8; ++j)
                s_sum += fabsf(rd[o][j] + 2.f * rd[o + 1][j] + rd[o + 2][j]);

        block_atomic_add(s_sum, acc + 2, s1);
    }
}

// Combine: out = W_C*c + W_R*r + W_P*p + W_S*s
__global__ void k_final(const float* __restrict__ acc, float* __restrict__ out) {
    const float r = acc[0] * (1.0f / 25165824.0f);  // mean over 8*3*1024*1024
    const float c = acc[1];
    const float s = acc[2];
    const float p = acc[3] * (1.0f / 524288.0f);    // mean over 8*256*256
    out[0] = 0.5f * c + 1.0f * r + 1.0f * p + 0.1f * s;
}

extern "C" void kernel_launch(void* const* d_in, const int* in_sizes, int n_in,
                              void* d_out, int out_size, void* d_ws, size_t ws_size,
                              hipStream_t stream) {
    const float* A = (const float*)d_in[0];  // predictions
    const float* B = (const float*)d_in[1];  // targets
    float* acc = (float*)d_ws;               // acc[0..3]

    hipMemsetAsync(acc, 0, 64 * sizeof(float), stream);
    hipLaunchKernelGGL(k_A,     dim3(NBLK), dim3(256), 0, stream, A, B, acc);
    hipLaunchKernelGGL(k_final, dim3(1),    dim3(1),   0, stream, acc, (float*)d_out);
}